// Round 1
// baseline (394.167 us; speedup 1.0000x reference)
//
#include <hip/hip_runtime.h>

#define HDIM 1024
#define NR 6   // effective output rows: 2 joint + 2 (group 0) + 2 (group 1)

// ---------------------------------------------------------------------------
// Kernel 1: A[6][H] = W2 @ W_phi  (W2 rows = [W_joint(2); W_groups(4)])
// blocks 0..63: 4 col-groups x 16 h-chunks, atomicAdd partials into A (ws).
// block 64: bias_eff[r] = W2[r,:]·b_phi + b2[r]
// ---------------------------------------------------------------------------
__global__ __launch_bounds__(256) void precompute_kernel(
    const float* __restrict__ Wphi, const float* __restrict__ bphi,
    const float* __restrict__ Wg,  const float* __restrict__ bg,
    const float* __restrict__ Wj,  const float* __restrict__ bj,
    float* __restrict__ A, float* __restrict__ biasEff)
{
    __shared__ float red[256];
    const int t = threadIdx.x;

    if (blockIdx.x == 64) {
        // bias block
        for (int r = 0; r < NR; ++r) {
            const float* w2 = (r < 2) ? (Wj + r * HDIM) : (Wg + (r - 2) * HDIM);
            float s = 0.f;
            for (int h = t; h < HDIM; h += 256) s += w2[h] * bphi[h];
            red[t] = s; __syncthreads();
            for (int off = 128; off > 0; off >>= 1) {
                if (t < off) red[t] += red[t + off];
                __syncthreads();
            }
            if (t == 0) {
                float b2 = (r < 2) ? bj[r] : bg[r - 2];
                biasEff[r] = red[0] + b2;
            }
            __syncthreads();
        }
        return;
    }

    const int cb  = blockIdx.x & 3;    // column group (256 cols each)
    const int hb  = blockIdx.x >> 2;   // h chunk (64 rows each, 16 chunks)
    const int col = cb * 256 + t;

    float acc[NR];
    #pragma unroll
    for (int r = 0; r < NR; ++r) acc[r] = 0.f;

    const int h0 = hb * 64;
    #pragma unroll 4
    for (int i = 0; i < 64; ++i) {
        const int h = h0 + i;
        const float w = Wphi[(size_t)h * HDIM + col];   // coalesced across t
        acc[0] += Wj[h]            * w;
        acc[1] += Wj[HDIM + h]     * w;
        acc[2] += Wg[h]            * w;
        acc[3] += Wg[HDIM + h]     * w;
        acc[4] += Wg[2 * HDIM + h] * w;
        acc[5] += Wg[3 * HDIM + h] * w;
    }
    #pragma unroll
    for (int r = 0; r < NR; ++r) atomicAdd(&A[r * HDIM + col], acc[r]);
}

// ---------------------------------------------------------------------------
// Kernel 2: Y[b,0:6] = X[b,:] @ A.T + bias_eff; gather by D / D_agn; write
//   out[0      .. 2B)  = joint        (rows 0,1)
//   out[2B     .. 4B)  = group_specific (rows 2+2*D[b]   + c)
//   out[4B     .. 6B)  = group_agnostic (rows 2+2*Dagn[b] + c)
// One wave per row; lane l owns cols {4l+256j+k}; A kept in registers.
// ---------------------------------------------------------------------------
__global__ __launch_bounds__(256, 3) void main_kernel(
    const float* __restrict__ X, const int* __restrict__ D,
    const int* __restrict__ Dagn,
    const float* __restrict__ A, const float* __restrict__ biasEff,
    float* __restrict__ out, int B)
{
    const int lane  = threadIdx.x & 63;
    const int wave  = threadIdx.x >> 6;
    const int gwave = blockIdx.x * 4 + wave;
    const int nwav  = gridDim.x * 4;

    // A fragments in registers: 6 rows x 4 float4 = 96 VGPRs
    float4 a[NR][4];
    #pragma unroll
    for (int r = 0; r < NR; ++r) {
        const float4* Ar = (const float4*)(A + r * HDIM);
        #pragma unroll
        for (int j = 0; j < 4; ++j) a[r][j] = Ar[lane + 64 * j];
    }
    float be[NR];
    #pragma unroll
    for (int r = 0; r < NR; ++r) be[r] = biasEff[r];

    for (int b = gwave; b < B; b += nwav) {
        const float4* xr = (const float4*)(X + (size_t)b * HDIM);
        float4 x[4];
        #pragma unroll
        for (int j = 0; j < 4; ++j) x[j] = xr[lane + 64 * j];  // coalesced 1KB/instr

        float acc[NR];
        #pragma unroll
        for (int r = 0; r < NR; ++r) {
            float s = 0.f;
            #pragma unroll
            for (int j = 0; j < 4; ++j) {
                s += x[j].x * a[r][j].x + x[j].y * a[r][j].y
                   + x[j].z * a[r][j].z + x[j].w * a[r][j].w;
            }
            acc[r] = s;
        }

        // 64-lane butterfly reduction for each of the 6 accumulators
        #pragma unroll
        for (int r = 0; r < NR; ++r) {
            float v = acc[r];
            #pragma unroll
            for (int off = 32; off > 0; off >>= 1)
                v += __shfl_xor(v, off, 64);
            acc[r] = v;
        }

        if (lane == 0) {
            const int d  = D[b]    & 1;
            const int da = Dagn[b] & 1;
            float y[NR];
            #pragma unroll
            for (int r = 0; r < NR; ++r) y[r] = acc[r] + be[r];
            float2* o = (float2*)out;
            o[b]         = make_float2(y[0], y[1]);
            o[B + b]     = make_float2(y[2 + 2 * d],  y[3 + 2 * d]);
            o[2 * B + b] = make_float2(y[2 + 2 * da], y[3 + 2 * da]);
        }
    }
}

extern "C" void kernel_launch(void* const* d_in, const int* in_sizes, int n_in,
                              void* d_out, int out_size, void* d_ws, size_t ws_size,
                              hipStream_t stream) {
    const float* X    = (const float*)d_in[0];
    const float* Wphi = (const float*)d_in[1];
    const float* bphi = (const float*)d_in[2];
    const float* Wg   = (const float*)d_in[3];
    const float* bg   = (const float*)d_in[4];
    const float* Wj   = (const float*)d_in[5];
    const float* bj   = (const float*)d_in[6];
    const int*   D    = (const int*)d_in[7];
    const int*   Dagn = (const int*)d_in[8];
    float* out = (float*)d_out;

    const int B = in_sizes[7];  // 65536

    float* A       = (float*)d_ws;          // 6*1024 floats
    float* biasEff = A + NR * HDIM;         // 6 floats

    // ws is poisoned 0xAA before every launch — zero the accumulator.
    hipMemsetAsync(A, 0, NR * HDIM * sizeof(float), stream);

    precompute_kernel<<<65, 256, 0, stream>>>(Wphi, bphi, Wg, bg, Wj, bj, A, biasEff);
    main_kernel<<<1024, 256, 0, stream>>>(X, D, Dagn, A, biasEff, out, B);
}

// Round 2
// 388.125 us; speedup vs baseline: 1.0156x; 1.0156x over previous
//
#include <hip/hip_runtime.h>

#define HDIM 1024
#define NR 6   // effective output rows: 2 joint + 2 (group 0) + 2 (group 1)

// ---------------------------------------------------------------------------
// Kernel 1: A[6][H] = W2 @ W_phi  (W2 rows = [W_joint(2); W_groups(4)])
// blocks 0..63: block cb owns 16 columns, full K range, LDS-reduced over 16
// k-slices -> direct store (no atomics, no zero-init needed).
// block 64: bias_eff[r] = W2[r,:]·b_phi + b2[r]
// ---------------------------------------------------------------------------
__global__ __launch_bounds__(256) void precompute_kernel(
    const float* __restrict__ Wphi, const float* __restrict__ bphi,
    const float* __restrict__ Wg,  const float* __restrict__ bg,
    const float* __restrict__ Wj,  const float* __restrict__ bj,
    float* __restrict__ A, float* __restrict__ biasEff)
{
    __shared__ float red[256][NR];
    const int t = threadIdx.x;

    if (blockIdx.x == 64) {
        // bias block: biasEff[r] = dot(W2[r], b_phi) + b2[r]
        __shared__ float rb[256];
        for (int r = 0; r < NR; ++r) {
            const float* w2 = (r < 2) ? (Wj + r * HDIM) : (Wg + (r - 2) * HDIM);
            float s = 0.f;
            for (int h = t; h < HDIM; h += 256) s += w2[h] * bphi[h];
            rb[t] = s; __syncthreads();
            for (int off = 128; off > 0; off >>= 1) {
                if (t < off) rb[t] += rb[t + off];
                __syncthreads();
            }
            if (t == 0) {
                float b2 = (r < 2) ? bj[r] : bg[r - 2];
                biasEff[r] = rb[0] + b2;
            }
            __syncthreads();
        }
        return;
    }

    const int cb  = blockIdx.x;        // 16 columns per block
    const int col = cb * 16 + (t & 15);
    const int ks  = t >> 4;            // 16 k-slices of 64 h each

    float acc[NR];
    #pragma unroll
    for (int r = 0; r < NR; ++r) acc[r] = 0.f;

    const int h0 = ks * 64;
    #pragma unroll 4
    for (int i = 0; i < 64; ++i) {
        const int h = h0 + i;
        const float w = Wphi[(size_t)h * HDIM + col];
        acc[0] += Wj[h]            * w;
        acc[1] += Wj[HDIM + h]     * w;
        acc[2] += Wg[h]            * w;
        acc[3] += Wg[HDIM + h]     * w;
        acc[4] += Wg[2 * HDIM + h] * w;
        acc[5] += Wg[3 * HDIM + h] * w;
    }
    #pragma unroll
    for (int r = 0; r < NR; ++r) red[t][r] = acc[r];
    __syncthreads();

    if (t < 16 * NR) {
        const int c = t & 15;
        const int r = t >> 4;          // 0..5
        float s = 0.f;
        #pragma unroll
        for (int k = 0; k < 16; ++k) s += red[k * 16 + c][r];
        A[r * HDIM + cb * 16 + c] = s;
    }
}

// ---------------------------------------------------------------------------
// Kernel 2: Y[b,0:6] = X[b,:] @ A.T + bias_eff; gather by D / D_agn; write
//   out[0    .. 2B) = joint (rows 0,1)
//   out[2B   .. 4B) = group_specific (rows 2+2*D[b]+c)
//   out[4B   .. 6B) = group_agnostic (rows 2+2*Dagn[b]+c)
// One wave per row; A held in registers (96 VGPRs); 64-lane butterfly reduce.
// grid=768 blocks -> 3072 waves = exactly resident at 3 blocks/CU, no tail.
// ---------------------------------------------------------------------------
__global__ __launch_bounds__(256, 3) void main_kernel(
    const float* __restrict__ X, const int* __restrict__ D,
    const int* __restrict__ Dagn,
    const float* __restrict__ A, const float* __restrict__ biasEff,
    float* __restrict__ out, int B)
{
    const int lane  = threadIdx.x & 63;
    const int wave  = threadIdx.x >> 6;
    const int gwave = blockIdx.x * 4 + wave;
    const int nwav  = gridDim.x * 4;

    // A fragments in registers: 6 rows x 4 float4 = 96 VGPRs
    float4 a[NR][4];
    #pragma unroll
    for (int r = 0; r < NR; ++r) {
        const float4* Ar = (const float4*)(A + r * HDIM);
        #pragma unroll
        for (int j = 0; j < 4; ++j) a[r][j] = Ar[lane + 64 * j];
    }
    float be[NR];
    #pragma unroll
    for (int r = 0; r < NR; ++r) be[r] = biasEff[r];

    for (int b = gwave; b < B; b += nwav) {
        const float4* xr = (const float4*)(X + (size_t)b * HDIM);
        float4 x[4];
        #pragma unroll
        for (int j = 0; j < 4; ++j) x[j] = xr[lane + 64 * j];  // 1KB/instr coalesced

        float acc[NR];
        #pragma unroll
        for (int r = 0; r < NR; ++r) {
            float s = 0.f;
            #pragma unroll
            for (int j = 0; j < 4; ++j) {
                s += x[j].x * a[r][j].x + x[j].y * a[r][j].y
                   + x[j].z * a[r][j].z + x[j].w * a[r][j].w;
            }
            acc[r] = s;
        }

        // 64-lane butterfly reduction, 6 independent chains
        #pragma unroll
        for (int r = 0; r < NR; ++r) {
            float v = acc[r];
            #pragma unroll
            for (int off = 32; off > 0; off >>= 1)
                v += __shfl_xor(v, off, 64);
            acc[r] = v;
        }

        if (lane == 0) {
            const int d  = D[b]    & 1;
            const int da = Dagn[b] & 1;
            float y[NR];
            #pragma unroll
            for (int r = 0; r < NR; ++r) y[r] = acc[r] + be[r];
            float2* o = (float2*)out;
            o[b]         = make_float2(y[0], y[1]);
            o[B + b]     = make_float2(y[2 + 2 * d],  y[3 + 2 * d]);
            o[2 * B + b] = make_float2(y[2 + 2 * da], y[3 + 2 * da]);
        }
    }
}

extern "C" void kernel_launch(void* const* d_in, const int* in_sizes, int n_in,
                              void* d_out, int out_size, void* d_ws, size_t ws_size,
                              hipStream_t stream) {
    const float* X    = (const float*)d_in[0];
    const float* Wphi = (const float*)d_in[1];
    const float* bphi = (const float*)d_in[2];
    const float* Wg   = (const float*)d_in[3];
    const float* bg   = (const float*)d_in[4];
    const float* Wj   = (const float*)d_in[5];
    const float* bj   = (const float*)d_in[6];
    const int*   D    = (const int*)d_in[7];
    const int*   Dagn = (const int*)d_in[8];
    float* out = (float*)d_out;

    const int B = in_sizes[7];  // 65536

    float* A       = (float*)d_ws;          // 6*1024 floats (fully overwritten)
    float* biasEff = A + NR * HDIM;         // 6 floats (fully overwritten)

    precompute_kernel<<<65, 256, 0, stream>>>(Wphi, bphi, Wg, bg, Wj, bj, A, biasEff);
    main_kernel<<<768, 256, 0, stream>>>(X, D, Dagn, A, biasEff, out, B);
}